// Round 1
// baseline (362.519 us; speedup 1.0000x reference)
//
#include <hip/hip_runtime.h>
#include <stdint.h>

#define NCH   1024
#define HW    65536   // 256*256 elements per channel
#define TOPK  256

// ---------------------------------------------------------------------------
// Kernel 1: per-channel mean. One block per channel; 256 threads each read
// 64 float4 (16 B/lane coalesced), accumulate in double for accuracy vs the
// numpy pairwise-fp32 reference (output is *indices*, so ordering must match
// exactly at the rank-256 boundary).
// ---------------------------------------------------------------------------
__global__ __launch_bounds__(256) void channel_mean_kernel(
    const float* __restrict__ x, float* __restrict__ means) {
    const int c   = blockIdx.x;
    const int tid = threadIdx.x;
    const float4* p = (const float4*)(x + (size_t)c * HW);

    double acc = 0.0;
    #pragma unroll 4
    for (int i = tid; i < HW / 4; i += 256) {
        float4 v = p[i];
        acc += (double)v.x + (double)v.y + (double)v.z + (double)v.w;
    }

    // wave (64-lane) shuffle reduction
    #pragma unroll
    for (int off = 32; off > 0; off >>= 1)
        acc += __shfl_down(acc, off, 64);

    __shared__ double lds[4];
    const int wave = tid >> 6;
    const int lane = tid & 63;
    if (lane == 0) lds[wave] = acc;
    __syncthreads();
    if (tid == 0) {
        double s = lds[0] + lds[1] + lds[2] + lds[3];
        means[c] = (float)(s / (double)HW);
    }
}

// ---------------------------------------------------------------------------
// Kernel 2: full descending bitonic sort of 1024 (mean, index) keys in LDS.
// Key = (ordered_uint(float) << 32) | (0xFFFFFFFF - idx): descending sort
// gives descending means with ties broken by LOWER index first, matching
// jax.lax.top_k's stable semantics.
// ---------------------------------------------------------------------------
__global__ __launch_bounds__(1024) void topk_kernel(
    const float* __restrict__ means, int* __restrict__ out) {
    __shared__ unsigned long long keys[NCH];
    const int tid = threadIdx.x;

    float f = means[tid];
    unsigned int u = __float_as_uint(f);
    u = (u & 0x80000000u) ? ~u : (u | 0x80000000u);  // order-preserving map
    keys[tid] = ((unsigned long long)u << 32) |
                (unsigned long long)(0xFFFFFFFFu - (unsigned)tid);
    __syncthreads();

    for (int k = 2; k <= NCH; k <<= 1) {
        for (int j = k >> 1; j > 0; j >>= 1) {
            const int ixj = tid ^ j;
            if (ixj > tid) {
                unsigned long long a = keys[tid];
                unsigned long long b = keys[ixj];
                const bool descending = ((tid & k) == 0);
                if ((a < b) == descending) {
                    keys[tid] = b;
                    keys[ixj] = a;
                }
            }
            __syncthreads();
        }
    }

    if (tid < TOPK) {
        out[tid] = (int)(0xFFFFFFFFu - (unsigned)(keys[tid] & 0xFFFFFFFFull));
    }
}

extern "C" void kernel_launch(void* const* d_in, const int* in_sizes, int n_in,
                              void* d_out, int out_size, void* d_ws, size_t ws_size,
                              hipStream_t stream) {
    const float* x   = (const float*)d_in[0];
    float* means     = (float*)d_ws;     // 1024 floats of scratch
    int*   out       = (int*)d_out;      // 256 int32 indices

    channel_mean_kernel<<<NCH, 256, 0, stream>>>(x, means);
    topk_kernel<<<1, 1024, 0, stream>>>(means, out);
}

// Round 2
// 355.837 us; speedup vs baseline: 1.0188x; 1.0188x over previous
//
#include <hip/hip_runtime.h>
#include <stdint.h>

#define NCH    1024
#define HW     65536    // 256*256 floats per channel
#define TOPK   256
#define PARTS  4        // blocks per channel
#define BLK    256      // threads per partial block
// each block sums HW/PARTS = 16384 floats = 4096 float4; 16 float4/thread

// ---------------------------------------------------------------------------
// Kernel 1: per-channel partial sums. 4 blocks per channel -> 4096 blocks
// (16 blocks/CU, full 32-wave occupancy). 4 independent fp64 accumulators
// break the dependency chain; 4 loads in flight per thread.
// ---------------------------------------------------------------------------
__global__ __launch_bounds__(BLK) void channel_partial_kernel(
    const float* __restrict__ x, double* __restrict__ partials) {
    const int b    = blockIdx.x;
    const int c    = b >> 2;         // channel
    const int part = b & 3;          // quarter within channel
    const int tid  = threadIdx.x;

    const float4* p = (const float4*)(x + ((size_t)c << 16) + ((size_t)part << 14));

    double a0 = 0.0, a1 = 0.0, a2 = 0.0, a3 = 0.0;
    #pragma unroll
    for (int t = 0; t < 16; t += 4) {
        float4 v0 = p[tid + (t + 0) * BLK];
        float4 v1 = p[tid + (t + 1) * BLK];
        float4 v2 = p[tid + (t + 2) * BLK];
        float4 v3 = p[tid + (t + 3) * BLK];
        a0 += (double)v0.x + (double)v0.y + (double)v0.z + (double)v0.w;
        a1 += (double)v1.x + (double)v1.y + (double)v1.z + (double)v1.w;
        a2 += (double)v2.x + (double)v2.y + (double)v2.z + (double)v2.w;
        a3 += (double)v3.x + (double)v3.y + (double)v3.z + (double)v3.w;
    }
    double acc = (a0 + a1) + (a2 + a3);

    // wave (64-lane) shuffle reduction
    #pragma unroll
    for (int off = 32; off > 0; off >>= 1)
        acc += __shfl_down(acc, off, 64);

    __shared__ double lds[BLK / 64];
    const int wave = tid >> 6;
    const int lane = tid & 63;
    if (lane == 0) lds[wave] = acc;
    __syncthreads();
    if (tid == 0) {
        double s = ((lds[0] + lds[1]) + lds[2]) + lds[3];
        partials[b] = s;
    }
}

// ---------------------------------------------------------------------------
// Kernel 2: combine partials -> mean, then descending bitonic sort of 1024
// (mean, index) keys. Stages with j<=32 are intra-wave (wave64) -> register
// shuffles, no barriers. LDS exchange only for j>=64 (10 stages, 20 barriers
// vs 55 for the naive version).
// Key = (ordered_uint(float) << 32) | (0xFFFFFFFF - idx): descending sort
// gives descending means, ties broken by lower index (matches lax.top_k).
// ---------------------------------------------------------------------------
__device__ __forceinline__ unsigned long long bitonic_step(
    unsigned long long key, unsigned long long partner, int tid, int k, int j) {
    const bool keep_max = (((tid & k) == 0) == ((tid & j) == 0));
    if (keep_max) return (key > partner) ? key : partner;
    return (key < partner) ? key : partner;
}

__global__ __launch_bounds__(1024) void topk_kernel(
    const double* __restrict__ partials, int* __restrict__ out) {
    __shared__ unsigned long long keys[NCH];
    const int tid = threadIdx.x;

    // deterministic combine of the 4 partials (fixed left-to-right order)
    const double* p = partials + (size_t)tid * PARTS;
    double s = ((p[0] + p[1]) + p[2]) + p[3];
    float f = (float)(s * (1.0 / (double)HW));

    unsigned int u = __float_as_uint(f);
    u = (u & 0x80000000u) ? ~u : (u | 0x80000000u);  // order-preserving map
    unsigned long long key = ((unsigned long long)u << 32) |
                             (unsigned long long)(0xFFFFFFFFu - (unsigned)tid);

    // phases k=2..64: entirely intra-wave (j<=32)
    #pragma unroll
    for (int k = 2; k <= 64; k <<= 1) {
        #pragma unroll
        for (int j = k >> 1; j > 0; j >>= 1) {
            unsigned long long partner = __shfl_xor(key, j, 64);
            key = bitonic_step(key, partner, tid, k, j);
        }
    }

    // phases k=128..1024: LDS exchange for j>=64, shuffles for j<=32
    #pragma unroll
    for (int k = 128; k <= 1024; k <<= 1) {
        for (int j = k >> 1; j >= 64; j >>= 1) {
            __syncthreads();               // previous readers done
            keys[tid] = key;
            __syncthreads();
            unsigned long long partner = keys[tid ^ j];
            key = bitonic_step(key, partner, tid, k, j);
        }
        #pragma unroll
        for (int j = 32; j > 0; j >>= 1) {
            unsigned long long partner = __shfl_xor(key, j, 64);
            key = bitonic_step(key, partner, tid, k, j);
        }
    }

    if (tid < TOPK) {
        out[tid] = (int)(0xFFFFFFFFu - (unsigned)(key & 0xFFFFFFFFull));
    }
}

extern "C" void kernel_launch(void* const* d_in, const int* in_sizes, int n_in,
                              void* d_out, int out_size, void* d_ws, size_t ws_size,
                              hipStream_t stream) {
    const float* x     = (const float*)d_in[0];
    double* partials   = (double*)d_ws;   // 4096 doubles of scratch
    int*    out        = (int*)d_out;     // 256 int32 indices

    channel_partial_kernel<<<NCH * PARTS, BLK, 0, stream>>>(x, partials);
    topk_kernel<<<1, NCH, 0, stream>>>(partials, out);
}